// Round 11
// baseline (149.621 us; speedup 1.0000x reference)
//
#include <hip/hip_runtime.h>
#include <hip/hip_bf16.h>

#define H 8
#define D 32
#define HD 256            // H*D floats per edge/node row
#define NEG_SLOPE 0.01f
#define BCAP 16           // bucket capacity per node; P(Poisson(5) > 16) ~ 2e-6
#define OVF_CAP 8192      // overflow pairs (node,edge) — expected ~0 used

typedef float f32x4 __attribute__((ext_vector_type(4)));
typedef int   i32x4 __attribute__((ext_vector_type(4)));

// ---------------- single-pass bucket CSR build ----------------
// slot = atomicAdd(cursor[dst]); slots < BCAP go to bucket[dst*BCAP+slot],
// the (vanishingly rare) rest to a global overflow list. cursor ends = degree.
__global__ void bucket_scatter_kernel(const int* __restrict__ dst, int E,
                                      int* __restrict__ cursor,
                                      int* __restrict__ bucket,
                                      int* __restrict__ ovf_cnt,
                                      int* __restrict__ ovf) {
    int i = blockIdx.x * blockDim.x + threadIdx.x;
    int base = i * 4;
#define PUT(d, e) { \
    int slot = atomicAdd(&cursor[d], 1); \
    if (slot < BCAP) bucket[(size_t)(d) * BCAP + slot] = (e); \
    else { int p = atomicAdd(ovf_cnt, 1); \
           if (p < OVF_CAP) { ovf[2 * p] = (d); ovf[2 * p + 1] = (e); } } }
    if (base + 3 < E) {
        i32x4 d = __builtin_nontemporal_load(reinterpret_cast<const i32x4*>(dst + base));
        PUT(d.x, base)
        PUT(d.y, base + 1)
        PUT(d.z, base + 2)
        PUT(d.w, base + 3)
    } else {
        for (int k = base; k < E; ++k) PUT(dst[k], k)
    }
#undef PUT
}

// ---------------- fused score + softmax + aggregate + ELU ----------------
// One wave (64 lanes) per destination node. Lane l owns floats [4l,4l+4)
// of the 256-float row -> head = l/8; the 8-lane group covers one head's dims.
//
// Startup-latency fixes this round:
//  - bucket row load index is (lane & 15): NO dependence on cursor[node], so
//    the cursor (len) and bucket (edge ids) L3 loads are concurrent
//  - slot-0 feat row issued unconditionally with clamped index, so the first
//    HBM load is in flight before len arrives (0.7% zero-degree waste)
//  - BCAP=16 -> two static depth-8 chunks, no inner loop
__global__ void aggregate_kernel(const float* __restrict__ feat,
                                 const float* __restrict__ attn_r,
                                 const int* __restrict__ bucket,
                                 const int* __restrict__ cursor,
                                 const int* __restrict__ ovf_cnt,
                                 const int* __restrict__ ovf,
                                 float* __restrict__ out, int N, int E) {
    int gtid = blockIdx.x * blockDim.x + threadIdx.x;
    int node = gtid >> 6;
    int lane = threadIdx.x & 63;
    if (node >= N) return;

    // two independent loads, both issued immediately
    int eidx = bucket[(size_t)node * BCAP + (lane & (BCAP - 1))];
    int len  = cursor[node];

    const f32x4* featv = reinterpret_cast<const f32x4*>(feat);

    // slot-0 feat row: unconditional, index clamped against garbage
    int e0 = __shfl(eidx, 0);
    e0 = min(max(e0, 0), E - 1);
    f32x4 f0 = __builtin_nontemporal_load(&featv[(size_t)e0 * 64 + lane]);

    f32x4 ar = reinterpret_cast<const f32x4*>(attn_r)[lane];

    f32x4 acc = (f32x4)(0.f);
    float den = 0.f;

#define LOADF(c, i, fi) if (rem > (c) + (i)) { int e = __shfl(eidx, (c) + (i)); \
    fi = __builtin_nontemporal_load(&featv[(size_t)e * 64 + lane]); }
#define PROC(fi) { \
    float part = fi.x * ar.x + fi.y * ar.y + fi.z * ar.z + fi.w * ar.w; \
    part += __shfl_xor(part, 1); \
    part += __shfl_xor(part, 2); \
    part += __shfl_xor(part, 4); \
    float el  = (part > 0.f) ? part : NEG_SLOPE * part; \
    float num = __expf(el); \
    den   += num; \
    acc.x += num * fi.x; acc.y += num * fi.y; \
    acc.z += num * fi.z; acc.w += num * fi.w; }

    int rem = min(len, BCAP);
    {
        // chunk 1: slots 0..7 (f0 already in flight)
        f32x4 f1, f2, f3, f4, f5, f6, f7;
        LOADF(0, 1, f1) LOADF(0, 2, f2) LOADF(0, 3, f3)
        LOADF(0, 4, f4) LOADF(0, 5, f5) LOADF(0, 6, f6) LOADF(0, 7, f7)
        if (rem > 0) PROC(f0)
        if (rem > 1) PROC(f1)
        if (rem > 2) PROC(f2)
        if (rem > 3) PROC(f3)
        if (rem > 4) PROC(f4)
        if (rem > 5) PROC(f5)
        if (rem > 6) PROC(f6)
        if (rem > 7) PROC(f7)
    }
    if (rem > 8) {
        // chunk 2: slots 8..15
        f32x4 g0, g1, g2, g3, g4, g5, g6, g7;
        LOADF(8, 0, g0) LOADF(8, 1, g1) LOADF(8, 2, g2) LOADF(8, 3, g3)
        LOADF(8, 4, g4) LOADF(8, 5, g5) LOADF(8, 6, g6) LOADF(8, 7, g7)
        PROC(g0)
        if (rem > 9)  PROC(g1)
        if (rem > 10) PROC(g2)
        if (rem > 11) PROC(g3)
        if (rem > 12) PROC(g4)
        if (rem > 13) PROC(g5)
        if (rem > 14) PROC(g6)
        if (rem > 15) PROC(g7)
    }
    if (len > BCAP) {
        // exact overflow handling (expected ~0 nodes): scan overflow pairs
        int novf = min(*ovf_cnt, OVF_CAP);
        for (int i2 = 0; i2 < novf; ++i2) {
            if (ovf[2 * i2] == node) {
                int e = ovf[2 * i2 + 1];
                f32x4 f = __builtin_nontemporal_load(&featv[(size_t)e * 64 + lane]);
                PROC(f)
            }
        }
    }
#undef LOADF
#undef PROC

    float inv = (len > 0) ? (1.0f / den) : 0.0f;  // zero-degree node -> out 0
    f32x4 o;
    o.x = acc.x * inv;
    o.y = acc.y * inv;
    o.z = acc.z * inv;
    o.w = acc.w * inv;
    // ELU
    o.x = (o.x > 0.f) ? o.x : expm1f(o.x);
    o.y = (o.y > 0.f) ? o.y : expm1f(o.y);
    o.z = (o.z > 0.f) ? o.z : expm1f(o.z);
    o.w = (o.w > 0.f) ? o.w : expm1f(o.w);
    __builtin_nontemporal_store(o, &reinterpret_cast<f32x4*>(out)[(size_t)node * 64 + lane]);
}

// ---------------- launch ----------------

extern "C" void kernel_launch(void* const* d_in, const int* in_sizes, int n_in,
                              void* d_out, int out_size, void* d_ws, size_t ws_size,
                              hipStream_t stream) {
    const float* feat   = (const float*)d_in[0];
    const float* attn_r = (const float*)d_in[1];
    const int*   dst    = (const int*)d_in[2];
    float*       out    = (float*)d_out;

    const int E = in_sizes[0] / HD;   // 500000
    const int N = out_size / HD;      // 100000

    // workspace layout (ints): bucket[N*BCAP] | cursor[N] | ovf_cnt[1] | ovf[2*OVF_CAP]
    int* bucket  = (int*)d_ws;
    int* cursor  = bucket + (size_t)N * BCAP;
    int* ovf_cnt = cursor + N;
    int* ovf     = ovf_cnt + 1;
    // total = (16N + N + 1 + 16384)*4 ~= 6.9 MB

    // zero cursor + ovf_cnt in one memset (adjacent)
    (void)hipMemsetAsync(cursor, 0, (size_t)(N + 1) * sizeof(int), stream);

    const int E4 = (E + 3) / 4;
    bucket_scatter_kernel<<<(E4 + 255) / 256, 256, 0, stream>>>(dst, E, cursor,
                                                                bucket, ovf_cnt, ovf);

    aggregate_kernel<<<(N + 3) / 4, 256, 0, stream>>>(feat, attn_r, bucket, cursor,
                                                      ovf_cnt, ovf, out, N, E);
}